// Round 7
// baseline (413.621 us; speedup 1.0000x reference)
//
#include <hip/hip_runtime.h>
#include <math.h>

// Problem constants
#define S_DIM 384
#define B_DIM 8
#define C_DIM 1024
#define H_DIM 16
#define M_DIM 1536
#define CC_DIM 64
#define ROWS  (S_DIM * B_DIM)      // 3072
#define N3C   (3 * C_DIM)          // 3072
#define CHUNK 6                    // chunks per attention split-block
#define MAXS  5                    // max splits per (b,h,sc):  ceil(30/6)=5

typedef unsigned short u16;
typedef short bf8v  __attribute__((ext_vector_type(8)));   // 8 bf16 (bit pattern)
typedef short bf4v  __attribute__((ext_vector_type(4)));   // 4 bf16
typedef u16   us8   __attribute__((ext_vector_type(8)));
typedef u16   us4   __attribute__((ext_vector_type(4)));
typedef float f4v   __attribute__((ext_vector_type(4)));

__device__ __forceinline__ u16 f2bf(float f) {
    unsigned u = __float_as_uint(f);
    u += 0x7fffu + ((u >> 16) & 1u);     // round-to-nearest-even
    return (u16)(u >> 16);
}
__device__ __forceinline__ float bf2f(u16 v) {
    return __uint_as_float(((unsigned)v) << 16);
}
#if __has_builtin(__builtin_amdgcn_exp2f)
#define EX2(x) __builtin_amdgcn_exp2f(x)
#else
#define EX2(x) __expf((x) * 0.69314718056f)
#endif
#define QSCALE (0.125f * 1.44269504f)    // 1/sqrt(64) * log2(e): softmax in exp2 domain

// v_cvt_pk_bf16_f32: 2 f32 -> 1 dword of 2 bf16 (RNE, same as f2bf). No builtin
// on gfx950 (learn_hip m240) — inline asm.
__device__ __forceinline__ unsigned cvtpk_bf16(float a, float b) {
    unsigned r;
    asm("v_cvt_pk_bf16_f32 %0, %1, %2" : "=v"(r) : "v"(a), "v"(b));
    return r;
}

// MFMA 16x16x16 bf16 wrapper: builtin exists in the DEVICE pass but
// __has_builtin is false in the HOST pass — host needs a body.
__device__ __forceinline__ f4v mfma16x16x16bf16(bf4v a, bf4v b, f4v c) {
#if __has_builtin(__builtin_amdgcn_mfma_f32_16x16x16bf16_1k)
    return __builtin_amdgcn_mfma_f32_16x16x16bf16_1k(a, b, c, 0, 0, 0);
#else
    return c;   // host-pass placeholder; never executed on device
#endif
}

// async global->LDS, 16B per lane; lds dest must be wave-contiguous (base+lane*16)
__device__ __forceinline__ void gload16(const u16* g, u16* l) {
    __builtin_amdgcn_global_load_lds(
        (const __attribute__((address_space(1))) void*)g,
        (__attribute__((address_space(3))) void*)l, 16, 0, 0);
}

// ---------------------------------------------------------------------------
// prep_all — byte-minimal: mem_len early-exit skips mk/mv rows t >= ceil64(L_b)
// (never read by attention). Full-line us8 transposed stores.
// ---------------------------------------------------------------------------
__device__ __forceinline__ void tr_direct8(const float* __restrict__ in,
                                           u16* __restrict__ out,
                                           int R, int Cc, int r0, int c0, int tid) {
    const int c4 = c0 + (tid & 15) * 4;
    const int rq = r0 + (tid >> 4) * 8;
    float4 L[8];
    #pragma unroll
    for (int k = 0; k < 8; k++)
        L[k] = *(const float4*)(in + (size_t)(rq + k) * Cc + c4);
    #pragma unroll
    for (int j = 0; j < 4; j++) {
        us8 o;
        #pragma unroll
        for (int k = 0; k < 8; k++)
            o[k] = f2bf(((const float*)&L[k])[j]);
        *(us8*)(out + (size_t)(c4 + j) * R + rq) = o;
    }
}

__global__ __launch_bounds__(256) void prep_all(
    const float* __restrict__ x, const float* __restrict__ pe, u16* __restrict__ Abf,
    const float* __restrict__ wqkv, u16* __restrict__ Wqkvt,
    const float* __restrict__ wout, u16* __restrict__ Woutt,
    const float* __restrict__ mk, u16* __restrict__ mk_bf,
    const float* __restrict__ mv, u16* __restrict__ mv_t,
    const unsigned char* __restrict__ terminal, const int* __restrict__ mem_len)
{
    const int bid = blockIdx.x, tid = threadIdx.x;

    if (bid < 1536) {                       // mv transpose (skip t0 >= Lc)
        const int bh = bid & 127, tg = bid >> 7;
        const int t0 = tg * 128;
        const int b = bh >> 4;
        const int L = terminal[b] ? 0 : mem_len[b];
        const int Lc = ((L + 63) >> 6) << 6;
        if (t0 >= Lc) return;
        const int cc4 = (tid & 15) * 4;
        const int tq = t0 + (tid >> 4) * 8;
        float4 Lv[8];
        #pragma unroll
        for (int k = 0; k < 8; k++)
            Lv[k] = *(const float4*)(mv + ((size_t)(tq + k) * 128 + bh) * 64 + cc4);
        #pragma unroll
        for (int j = 0; j < 4; j++) {
            us8 o;
            #pragma unroll
            for (int k = 0; k < 8; k++)
                o[k] = f2bf(((const float*)&Lv[k])[j]);
            *(us8*)(mv_t + ((size_t)bh * 64 + cc4 + j) * M_DIM + tq) = o;
        }
    } else if (bid < 4608) {                // mk cast per (b, 4 t-rows) (skip)
        const int b6 = bid - 1536;
        const int b = b6 & 7, t0 = (b6 >> 3) * 4;
        const int L = terminal[b] ? 0 : mem_len[b];
        const int Lc = ((L + 63) >> 6) << 6;
        if (t0 >= Lc) return;
        const int r = t0 + (tid >> 6);
        const size_t rb = (size_t)r * 8192 + (size_t)b * 1024;
        const int cw = (tid & 63) * 4;
        float4 v[4];
        #pragma unroll
        for (int j = 0; j < 4; j++)
            v[j] = *(const float4*)(mk + rb + cw + j * 256);
        #pragma unroll
        for (int j = 0; j < 4; j++) {
            us4 o;
            o[0] = f2bf(v[j].x); o[1] = f2bf(v[j].y);
            o[2] = f2bf(v[j].z); o[3] = f2bf(v[j].w);
            *(us4*)(mk_bf + rb + cw + j * 256) = o;
        }
    } else if (bid < 5376) {                // prep_a: 16 floats/thread
        size_t i0 = (size_t)(bid - 4608) * 4096 + tid * 16;
        float4 xv[4], pv[4];
        #pragma unroll
        for (int j = 0; j < 4; j++) {
            xv[j] = *(const float4*)(x + i0 + j * 4);
            pv[j] = *(const float4*)(pe + i0 + j * 4);
        }
        #pragma unroll
        for (int h8 = 0; h8 < 2; h8++) {
            us8 o;
            #pragma unroll
            for (int j = 0; j < 2; j++) {
                float4 a = xv[h8 * 2 + j], p = pv[h8 * 2 + j];
                o[j * 4 + 0] = f2bf(a.x + p.x);
                o[j * 4 + 1] = f2bf(a.y + p.y);
                o[j * 4 + 2] = f2bf(a.z + p.z);
                o[j * 4 + 3] = f2bf(a.w + p.w);
            }
            *(us8*)(Abf + i0 + h8 * 8) = o;
        }
    } else if (bid < 5760) {                // wqkv transpose (8 x 48 tiles)
        const int b2 = bid - 5376;
        tr_direct8(wqkv, Wqkvt, C_DIM, N3C, (b2 / 48) * 128, (b2 % 48) * 64, tid);
    } else {                                // wout transpose (8 x 16 tiles)
        const int b3 = bid - 5760;
        tr_direct8(wout, Woutt, C_DIM, C_DIM, (b3 / 16) * 128, (b3 % 16) * 64, tid);
    }
}

// ---------------------------------------------------------------------------
// qkv GEMM: 128x64 tiles, BK=64, swizzled DMA staging, LDS-transposed
// epilogue. Q/K bands: coalesced us8 row stores. V band: stores DIRECTLY
// TRANSPOSED to Vwt[bh][cc][s].
// ---------------------------------------------------------------------------
__global__ __launch_bounds__(256) void qkv_gemm(
    const u16* __restrict__ Abf, const u16* __restrict__ Wt,
    const float* __restrict__ bias,
    u16* __restrict__ Qw, u16* __restrict__ Kw, u16* __restrict__ Vwt)
{
    __shared__ u16 smem[128 * 64 + 64 * 64];   // As | Bs ; Cs aliases (128*72)
    u16* As = smem;
    u16* Bs = smem + 128 * 64;
    u16* Cs = smem;

    const int tid = threadIdx.x;
    const int lane = tid & 63, w = tid >> 6;
    const int lr = lane & 15, quad = lane >> 4;
    const int wm = w >> 1, wn = w & 1;
    const int row0 = blockIdx.y * 128, col0 = blockIdx.x * 64;

    f4v acc[4][2];
    #pragma unroll
    for (int i = 0; i < 4; i++)
        #pragma unroll
        for (int j = 0; j < 2; j++)
            acc[i][j] = (f4v){0.f, 0.f, 0.f, 0.f};

    for (int k0 = 0; k0 < C_DIM; k0 += 64) {
        __syncthreads();
        #pragma unroll
        for (int j = 0; j < 4; j++) {
            int idx = j * 256 + tid;
            int r = idx >> 3, c = (idx & 7) ^ (r & 7);
            gload16(&Abf[(size_t)(row0 + r) * C_DIM + k0 + c * 8], &As[idx * 8]);
        }
        #pragma unroll
        for (int j = 0; j < 2; j++) {
            int idx = j * 256 + tid;
            int r = idx >> 3, c = (idx & 7) ^ (r & 7);
            gload16(&Wt[(size_t)(col0 + r) * C_DIM + k0 + c * 8], &Bs[idx * 8]);
        }
        __syncthreads();
        #pragma unroll
        for (int kh = 0; kh < 2; kh++) {
            bf8v a[4], b[2];
            #pragma unroll
            for (int mi = 0; mi < 4; mi++) {
                int row = wm * 64 + mi * 16 + lr;
                int p = (kh * 4 + quad) ^ (lr & 7);
                a[mi] = *(const bf8v*)&As[row * 64 + p * 8];
            }
            #pragma unroll
            for (int nj = 0; nj < 2; nj++) {
                int row = wn * 32 + nj * 16 + lr;
                int p = (kh * 4 + quad) ^ (lr & 7);
                b[nj] = *(const bf8v*)&Bs[row * 64 + p * 8];
            }
            #pragma unroll
            for (int mi = 0; mi < 4; mi++)
                #pragma unroll
                for (int nj = 0; nj < 2; nj++)
                    acc[mi][nj] = __builtin_amdgcn_mfma_f32_16x16x32_bf16(a[mi], b[nj], acc[mi][nj], 0, 0, 0);
        }
    }

    const int which = col0 >> 10;
    const int h = (col0 >> 6) & 15;
    const float qs = (which == 0) ? QSCALE : 1.0f;

    __syncthreads();   // MFMA reads of As/Bs complete before Cs overwrite
    #pragma unroll
    for (int nj = 0; nj < 2; nj++) {
        int col = col0 + wn * 32 + nj * 16 + lr;
        float bv = bias[col];
        #pragma unroll
        for (int mi = 0; mi < 4; mi++)
            #pragma unroll
            for (int reg = 0; reg < 4; reg++)
                Cs[(wm * 64 + mi * 16 + quad * 4 + reg) * 72 + wn * 32 + nj * 16 + lr] =
                    f2bf((acc[mi][nj][reg] + bv) * qs);
    }
    __syncthreads();

    if (which != 2) {
        u16* dstbuf = (which == 0) ? Qw : Kw;
        int r = tid >> 1, half = tid & 1;
        int rg = row0 + r, s = rg >> 3, bb = rg & 7;
        u16* drow = dstbuf + ((size_t)(bb * 16 + h) * S_DIM + s) * 64 + half * 32;
        #pragma unroll
        for (int i = 0; i < 4; i++)
            *(us8*)(drow + i * 8) = *(const us8*)&Cs[r * 72 + half * 32 + i * 8];
    } else {
        int cc = tid & 63, w4 = tid >> 6;
        int s0 = row0 >> 3;
        #pragma unroll
        for (int pb = 0; pb < 2; pb++) {
            int bb = w4 * 2 + pb;
            us8 v0, v1;
            #pragma unroll
            for (int sl = 0; sl < 8; sl++) {
                v0[sl] = Cs[(sl * 8 + bb) * 72 + cc];
                v1[sl] = Cs[((sl + 8) * 8 + bb) * 72 + cc];
            }
            u16* dr = Vwt + ((size_t)(bb * 16 + h) * 64 + cc) * S_DIM + s0;
            *(us8*)dr = v0;
            *(us8*)(dr + 8) = v1;
        }
    }
}

// ---------------------------------------------------------------------------
// attn_split — R7: LDS-FREE, BARRIER-FREE. Evidence: R3 (prefetch), R4
// (1-barrier ring), R6 (half the staged bytes/iters) all NULL at ~47-51us;
// effective residency pinned at ~8.3 waves/CU; bank conflicts 3.19M (4.06/
// PV-read) constant. The invariant is the barrier-locked LDS staging pipe
// itself: 8 waves in lockstep re-reading the same 8KB K/V tiles from LDS.
// Fix: MFMA fragments load DIRECTLY global->VGPR (swizzle algebra collapses:
// k0=K[row][quad*8], k1=K[row][32+quad*8], vf=V[cc][tt*16+quad*4]); all
// coalesced (4 lanes per 64B line). No barriers, no LDS, no conflicts; waves
// fully independent (TLP hides latency; m191's setprio-positive regime).
// L1 serves the 8x intra-block tile reuse; L2/L3 back it.
// Geometry: back to R2 (256 thr, 64-row Q tiles, grid bhsc x MAXS).
// ---------------------------------------------------------------------------
__global__ __launch_bounds__(256) void attn_split(
    const u16* __restrict__ Qw, const u16* __restrict__ Kw,
    const u16* __restrict__ mk_bf, const u16* __restrict__ Vwt,
    const u16* __restrict__ mv_t, const unsigned char* __restrict__ terminal,
    const int* __restrict__ mem_len, u16* __restrict__ Op, float* __restrict__ ml)
{
    const int tid = threadIdx.x;
    const int lane = tid & 63, w = tid >> 6;
    const int lr = lane & 15, quad = lane >> 4, q8 = quad * 8;
    const int bid = blockIdx.x;
    const int j = bid % MAXS;
    const int g = bid / MAXS;                       // bhsc
    const int b = g & 7, h = (g >> 3) & 15, sc = g >> 7;
    const int bh = b * 16 + h, sq0 = sc * 64;
    const int L = terminal[b] ? 0 : mem_len[b];
    const int memChunks = (L + 63) >> 6;
    const int total = memChunks + sc + 1;
    const int lo = j * CHUNK;
    const int hi = (lo + CHUNK < total) ? lo + CHUNK : total;
    if (lo >= total) return;                        // inactive slot

    const int qrow = sq0 + w * 16 + lr;

    // Q as B-fragment (pre-scaled by QSCALE in qkv epilogue)
    const u16* qbase = Qw + ((size_t)bh * S_DIM + sq0 + w * 16 + lr) * 64;
    bf8v qf0 = *(const bf8v*)&qbase[q8];
    bf8v qf1 = *(const bf8v*)&qbase[32 + q8];

    f4v O[4];
    #pragma unroll
    for (int nj = 0; nj < 4; nj++) O[nj] = (f4v){0.f, 0.f, 0.f, 0.f};
    float m_i = -1e30f, l_i = 0.0f;

    const f4v zero = (f4v){0.f, 0.f, 0.f, 0.f};

    for (int ch = lo; ch < hi; ch++) {
        const bool isMem = (ch < memChunks);
        const int tloc = isMem ? ch * 64 : (ch - memChunks) * 64;
        const u16* kb; unsigned kstr;
        if (isMem) { kb = mk_bf + ((size_t)tloc * 128 + bh) * 64; kstr = 128u * 64u; }
        else       { kb = Kw + ((size_t)bh * S_DIM + tloc) * 64; kstr = 64u; }
        const u16* vb; unsigned vstr;
        if (isMem) { vb = mv_t + (size_t)bh * 64 * M_DIM + tloc; vstr = M_DIM; }
        else       { vb = Vwt + (size_t)bh * 64 * S_DIM + tloc; vstr = S_DIM; }

        // S^T tiles: sv[tt] covers t = tloc + tt*16 + quad*4 + reg, q = lane&15
        // K fragments: DIRECT global loads (row-coalesced, 4 lanes/64B line).
        f4v sv[4];
        __builtin_amdgcn_s_setprio(1);
        #pragma unroll
        for (int tt = 0; tt < 4; tt++) {
            unsigned row = tt * 16 + lr;
            bf8v k0 = *(const bf8v*)(kb + row * kstr + q8);
            bf8v k1 = *(const bf8v*)(kb + row * kstr + 32 + q8);
            sv[tt] = __builtin_amdgcn_mfma_f32_16x16x32_bf16(k0, qf0, zero, 0, 0, 0);
            sv[tt] = __builtin_amdgcn_mfma_f32_16x16x32_bf16(k1, qf1, sv[tt], 0, 0, 0);
        }
        __builtin_amdgcn_s_setprio(0);

        // Mask — wave-uniform skip (only boundary/diagonal chunks pay)
        if (isMem) {
            if (tloc + 64 > L) {
                #pragma unroll
                for (int tt = 0; tt < 4; tt++)
                    #pragma unroll
                    for (int reg = 0; reg < 4; reg++) {
                        int t = tloc + tt * 16 + quad * 4 + reg;
                        if (t >= L) sv[tt][reg] = -1e30f;
                    }
            }
        } else {
            if (tloc + 63 > sq0 + w * 16) {
                #pragma unroll
                for (int tt = 0; tt < 4; tt++)
                    #pragma unroll
                    for (int reg = 0; reg < 4; reg++) {
                        int t = tloc + tt * 16 + quad * 4 + reg;
                        if (t > qrow) sv[tt][reg] = -1e30f;
                    }
            }
        }

        // Online softmax, exp2 domain; reduce across lanes q,q+16,q+32,q+48
        float rowmax = fmaxf(fmaxf(sv[0][0], sv[0][1]), fmaxf(sv[0][2], sv[0][3]));
        #pragma unroll
        for (int tt = 1; tt < 4; tt++)
            rowmax = fmaxf(rowmax, fmaxf(fmaxf(sv[tt][0], sv[tt][1]),
                                         fmaxf(sv[tt][2], sv[tt][3])));
        rowmax = fmaxf(rowmax, __shfl_xor(rowmax, 16));
        rowmax = fmaxf(rowmax, __shfl_xor(rowmax, 32));

        // T13 defer-max: skip rescale when max grew by <= 8 (P bounded 2^8)
        const bool defer = __all(rowmax - m_i <= 8.0f);
        const float mnew = defer ? m_i : fmaxf(m_i, rowmax);

        float p[16];
        float s0 = 0.f, s1 = 0.f, s2 = 0.f, s3 = 0.f;
        #pragma unroll
        for (int tt = 0; tt < 4; tt++) {
            p[tt * 4 + 0] = EX2(sv[tt][0] - mnew);
            p[tt * 4 + 1] = EX2(sv[tt][1] - mnew);
            p[tt * 4 + 2] = EX2(sv[tt][2] - mnew);
            p[tt * 4 + 3] = EX2(sv[tt][3] - mnew);
            s0 += p[tt * 4 + 0]; s1 += p[tt * 4 + 1];
            s2 += p[tt * 4 + 2]; s3 += p[tt * 4 + 3];
        }
        float sum = (s0 + s1) + (s2 + s3);
        sum += __shfl_xor(sum, 16);
        sum += __shfl_xor(sum, 32);

        bf4v pf[4];
        #pragma unroll
        for (int tt = 0; tt < 4; tt++) {
            union { bf4v v; unsigned u[2]; } pu;
            pu.u[0] = cvtpk_bf16(p[tt * 4 + 0], p[tt * 4 + 1]);
            pu.u[1] = cvtpk_bf16(p[tt * 4 + 2], p[tt * 4 + 3]);
            pf[tt] = pu.v;
        }

        if (defer) {
            l_i += sum;                        // alpha == 1, O untouched
        } else {
            float alpha = EX2(m_i - mnew);
            m_i = mnew;
            l_i = l_i * alpha + sum;
            float alphaR[4];
            #pragma unroll
            for (int reg = 0; reg < 4; reg++)
                alphaR[reg] = __shfl(alpha, quad * 4 + reg);
            #pragma unroll
            for (int nj = 0; nj < 4; nj++)
                #pragma unroll
                for (int reg = 0; reg < 4; reg++)
                    O[nj][reg] *= alphaR[reg];
        }

        // PV: A = P (regs), B = V DIRECT global loads V[cc][tt*16+quad*4]
        // (32B/row consumed across tt pairs -> full-line L1 reuse)
        __builtin_amdgcn_s_setprio(1);
        #pragma unroll
        for (int tt = 0; tt < 4; tt++) {
            #pragma unroll
            for (int nj = 0; nj < 4; nj++) {
                unsigned cc = nj * 16 + lr;
                bf4v vf = *(const bf4v*)(vb + cc * vstr + tt * 16 + quad * 4);
                O[nj] = mfma16x16x16bf16(pf[tt], vf, O[nj]);
            }
        }
        __builtin_amdgcn_s_setprio(0);
    }

    // Write partials (unnormalized O, m, l) — slot (g, j)
    const size_t pbase = (size_t)(g * MAXS + j) * 64;
    if (quad == 0) {
        int row = w * 16 + lr;
        float2 mlv = {m_i, l_i};
        *(float2*)&ml[(pbase + row) * 2] = mlv;
    }
    #pragma unroll
    for (int reg = 0; reg < 4; reg++) {
        int row = w * 16 + quad * 4 + reg;
        #pragma unroll
        for (int nj = 0; nj < 4; nj++)
            Op[(pbase + row) * 64 + nj * 16 + lr] = f2bf(O[nj][reg]);
    }
}

// ---------------------------------------------------------------------------
// attn_combine: merge the valid slots (j*CHUNK < total_g) -> Obf bf16
// ---------------------------------------------------------------------------
__global__ __launch_bounds__(256) void attn_combine(
    const unsigned char* __restrict__ terminal, const int* __restrict__ mem_len,
    const u16* __restrict__ Op, const float* __restrict__ ml, u16* __restrict__ Obf)
{
    const int g = blockIdx.x;                       // bhsc
    const int b = g & 7, h = (g >> 3) & 15, sc = g >> 7;
    const int tid = threadIdx.x;
    const int row = tid >> 2, c0 = (tid & 3) * 16;

    const int L = terminal[b] ? 0 : mem_len[b];
    const int total = ((L + 63) >> 6) + sc + 1;
    const int nsp = (total + CHUNK - 1) / CHUNK;    // valid slots

    float m[MAXS], lv[MAXS];
    #pragma unroll
    for (int j = 0; j < MAXS; j++) {
        if (j < nsp) {
            size_t base = (size_t)(g * MAXS + j) * 64 + row;
            m[j]  = ml[base * 2];
            lv[j] = ml[base * 2 + 1];
        } else { m[j] = -1e30f; lv[j] = 0.0f; }
    }
    float mstar = m[0];
    #pragma unroll
    for (int j = 1; j < MAXS; j++) mstar = fmaxf(mstar, m[j]);
    float sc_j[MAXS], l = 0.0f;
    #pragma unroll
    for (int j = 0; j < MAXS; j++) {
        sc_j[j] = (j < nsp) ? EX2(m[j] - mstar) : 0.0f;   // exp2 domain
        l += sc_j[j] * lv[j];
    }
    float inv = 1.0f / l;

    float o[16];
    #pragma unroll
    for (int c = 0; c < 16; c++) o[c] = 0.0f;
    for (int j = 0; j < nsp; j++) {
        const u16* src = &Op[((size_t)(g * MAXS + j) * 64 + row) * 64 + c0];
        us8 v0 = *(const us8*)src;
        us8 v1 = *(const us8*)(src + 8);
        #pragma unroll
        for (int c = 0; c < 8; c++) {
            o[c]     += sc_j[j] * bf2f(v0[c]);
            o[c + 8] += sc_j[j] * bf2f(v1[c]);
        }
    }
    int s = sc * 64 + row;
    size_t dst = ((size_t)s * 8 + b) * C_DIM + h * 64 + c0;
    us8 w0, w1;
    #pragma unroll
    for (int c = 0; c < 8; c++) {
        w0[c] = f2bf(o[c] * inv);
        w1[c] = f2bf(o[c + 8] * inv);
    }
    *(us8*)&Obf[dst] = w0;
    *(us8*)&Obf[dst + 8] = w1;
}

// ---------------------------------------------------------------------------
// proj GEMM: 64x64 tiles, BK=64, swizzled DMA staging.
// ---------------------------------------------------------------------------
__global__ __launch_bounds__(256) void proj_gemm(
    const u16* __restrict__ Abf, const u16* __restrict__ Wt,
    const float* __restrict__ bias, float* __restrict__ out)
{
    __shared__ u16 As[64 * 64];
    __shared__ u16 Bs[64 * 64];
    const int tid = threadIdx.x;
    const int lane = tid & 63, w = tid >> 6;
    const int lr = lane & 15, quad = lane >> 4;
    const int row0 = blockIdx.y * 64, col0 = blockIdx.x * 64;

    f4v acc[4];
    #pragma unroll
    for (int i = 0; i < 4; i++) acc[i] = (f4v){0.f, 0.f, 0.f, 0.f};

    for (int k0 = 0; k0 < C_DIM; k0 += 64) {
        __syncthreads();
        #pragma unroll
        for (int j = 0; j < 2; j++) {
            int idx = j * 256 + tid;
            int r = idx >> 3, c = (idx & 7) ^ (r & 7);
            gload16(&Abf[(size_t)(row0 + r) * C_DIM + k0 + c * 8], &As[idx * 8]);
            gload16(&Wt[(size_t)(col0 + r) * C_DIM + k0 + c * 8], &Bs[idx * 8]);
        }
        __syncthreads();
        #pragma unroll
        for (int kh = 0; kh < 2; kh++) {
            int p = (kh * 4 + quad) ^ (lr & 7);
            bf8v a = *(const bf8v*)&As[(w * 16 + lr) * 64 + p * 8];
            #pragma unroll
            for (int nj = 0; nj < 4; nj++) {
                bf8v bfr = *(const bf8v*)&Bs[(nj * 16 + lr) * 64 + p * 8];
                acc[nj] = __builtin_amdgcn_mfma_f32_16x16x32_bf16(a, bfr, acc[nj], 0, 0, 0);
            }
        }
    }

    #pragma unroll
    for (int nj = 0; nj < 4; nj++) {
        int col = col0 + nj * 16 + lr;
        float bv = bias[col];
        #pragma unroll
        for (int reg = 0; reg < 4; reg++) {
            int rg = row0 + w * 16 + quad * 4 + reg;
            out[(size_t)rg * C_DIM + col] = acc[nj][reg] + bv;
        }
    }
}

// ---------------------------------------------------------------------------
extern "C" void kernel_launch(void* const* d_in, const int* in_sizes, int n_in,
                              void* d_out, int out_size, void* d_ws, size_t ws_size,
                              hipStream_t stream) {
    const float* x    = (const float*)d_in[0];
    const float* pe   = (const float*)d_in[1];
    const float* mk   = (const float*)d_in[2];
    const float* mv   = (const float*)d_in[3];
    const float* wqkv = (const float*)d_in[4];
    const float* bqkv = (const float*)d_in[5];
    const float* wout = (const float*)d_in[6];
    const float* bout = (const float*)d_in[7];
    const unsigned char* term = (const unsigned char*)d_in[8];
    // d_in[9] content_mask (causal, analytic), d_in[10] padding_mask (all False)
    const int* mem_len = (const int*)d_in[11];

    char* ws = (char*)d_ws;
    u16* Abf   = (u16*)(ws + 0);          // 6291456 B  (Obf aliases after qkv)
    u16* Obf   = (u16*)(ws + 0);
    u16* Wqkvt = (u16*)(ws + 6291456);    // 6291456 B  (ml aliases after qkv)
    float* ml  = (float*)(ws + 6291456);  // 1966080 B  (768*5*64*2 f32)
    u16* Woutt = (u16*)(ws + 12582912);   // 2097152 B
    u16* mk_bf = (u16*)(ws + 14680064);   // 25165824 B  [t][bh][cc] bf16 (cast only)
    u16* mv_t  = (u16*)(ws + 39845888);   // 25165824 B  [bh][cc][t]
    u16* Qw    = (u16*)(ws + 65011712);   // 6291456 B
    u16* Kw    = (u16*)(ws + 71303168);   // 6291456 B
    u16* Vwt   = (u16*)(ws + 77594624);   // 6291456 B  [bh][cc][s] (written by qkv)
    u16* Op    = (u16*)(ws + 83886080);   // 31457280 B (768*5*64*64 bf16) end 115343360

    float* out = (float*)d_out;

    prep_all<<<5888, 256, 0, stream>>>(x, pe, Abf, wqkv, Wqkvt, wout, Woutt,
                                       mk, mk_bf, mv, mv_t, term, mem_len);

    qkv_gemm<<<dim3(N3C / 64, ROWS / 128), 256, 0, stream>>>(
        Abf, Wqkvt, bqkv, Qw, Kw, Vwt);

    attn_split<<<B_DIM * H_DIM * (S_DIM / 64) * MAXS, 256, 0, stream>>>(
        Qw, Kw, mk_bf, Vwt, mv_t, term, mem_len, Op, ml);

    attn_combine<<<B_DIM * H_DIM * (S_DIM / 64), 256, 0, stream>>>(
        term, mem_len, Op, ml, Obf);

    proj_gemm<<<dim3(C_DIM / 64, ROWS / 64), 256, 0, stream>>>(
        Obf, Woutt, bout, out);
}

// Round 8
// 258.933 us; speedup vs baseline: 1.5974x; 1.5974x over previous
//
#include <hip/hip_runtime.h>
#include <math.h>

// Problem constants
#define S_DIM 384
#define B_DIM 8
#define C_DIM 1024
#define H_DIM 16
#define M_DIM 1536
#define CC_DIM 64
#define ROWS  (S_DIM * B_DIM)      // 3072
#define N3C   (3 * C_DIM)          // 3072
#define CHUNK 6                    // chunks per attention split-block
#define MAXS  5                    // max splits per (b,h,sc):  ceil(30/6)=5

typedef unsigned short u16;
typedef short bf8v  __attribute__((ext_vector_type(8)));   // 8 bf16 (bit pattern)
typedef short bf4v  __attribute__((ext_vector_type(4)));   // 4 bf16
typedef u16   us8   __attribute__((ext_vector_type(8)));
typedef u16   us4   __attribute__((ext_vector_type(4)));
typedef float f4v   __attribute__((ext_vector_type(4)));

__device__ __forceinline__ u16 f2bf(float f) {
    unsigned u = __float_as_uint(f);
    u += 0x7fffu + ((u >> 16) & 1u);     // round-to-nearest-even
    return (u16)(u >> 16);
}
__device__ __forceinline__ float bf2f(u16 v) {
    return __uint_as_float(((unsigned)v) << 16);
}
#if __has_builtin(__builtin_amdgcn_exp2f)
#define EX2(x) __builtin_amdgcn_exp2f(x)
#else
#define EX2(x) __expf((x) * 0.69314718056f)
#endif
#define QSCALE (0.125f * 1.44269504f)    // 1/sqrt(64) * log2(e): softmax in exp2 domain

// v_cvt_pk_bf16_f32: 2 f32 -> 1 dword of 2 bf16 (RNE, same as f2bf).
__device__ __forceinline__ unsigned cvtpk_bf16(float a, float b) {
    unsigned r;
    asm("v_cvt_pk_bf16_f32 %0, %1, %2" : "=v"(r) : "v"(a), "v"(b));
    return r;
}

// MFMA 16x16x16 bf16 wrapper (host pass lacks the builtin).
__device__ __forceinline__ f4v mfma16x16x16bf16(bf4v a, bf4v b, f4v c) {
#if __has_builtin(__builtin_amdgcn_mfma_f32_16x16x16bf16_1k)
    return __builtin_amdgcn_mfma_f32_16x16x16bf16_1k(a, b, c, 0, 0, 0);
#else
    return c;   // host-pass placeholder; never executed on device
#endif
}

// async global->LDS, 16B per lane; lds dest must be wave-contiguous
__device__ __forceinline__ void gload16(const u16* g, u16* l) {
    __builtin_amdgcn_global_load_lds(
        (const __attribute__((address_space(1))) void*)g,
        (__attribute__((address_space(3))) void*)l, 16, 0, 0);
}

// ---------------------------------------------------------------------------
// R8 restructure: overlap instead of optimize. Dependency analysis:
//   prep_a + wqkv^T -> qkv_gemm    (must precede kernel 2)
//   mk, mv          -> attn_split  (kernel 3) — INDEPENDENT of qkv_gemm
//   wout^T          -> proj_gemm   (kernel 5) — INDEPENDENT of qkv_gemm
// So mk/mv/wout prep blocks are APPENDED to the qkv dispatch: memory-only
// blocks co-scheduled with MFMA-heavy GEMM blocks overlap (m114). Serial
// prep 47us collapses to ~10us (prep_early) + absorbed remainder.
// attn_split reverted to proven best (R5-V2 structure, 47.0us) after R7's
// LDS-free experiment regressed 4x (global-gather latency-serialized).
// ---------------------------------------------------------------------------

// prep_early: [0,768) prep_a (Abf = bf16(x+pe)); [768,1152) wqkv^T.
__device__ __forceinline__ void tr_direct8(const float* __restrict__ in,
                                           u16* __restrict__ out,
                                           int R, int Cc, int r0, int c0, int tid) {
    const int c4 = c0 + (tid & 15) * 4;
    const int rq = r0 + (tid >> 4) * 8;
    float4 L[8];
    #pragma unroll
    for (int k = 0; k < 8; k++)
        L[k] = *(const float4*)(in + (size_t)(rq + k) * Cc + c4);
    #pragma unroll
    for (int j = 0; j < 4; j++) {
        us8 o;
        #pragma unroll
        for (int k = 0; k < 8; k++)
            o[k] = f2bf(((const float*)&L[k])[j]);
        *(us8*)(out + (size_t)(c4 + j) * R + rq) = o;
    }
}

__global__ __launch_bounds__(256) void prep_early(
    const float* __restrict__ x, const float* __restrict__ pe, u16* __restrict__ Abf,
    const float* __restrict__ wqkv, u16* __restrict__ Wqkvt)
{
    const int bid = blockIdx.x, tid = threadIdx.x;
    if (bid < 768) {                        // prep_a: 16 floats/thread
        size_t i0 = (size_t)bid * 4096 + tid * 16;
        float4 xv[4], pv[4];
        #pragma unroll
        for (int j = 0; j < 4; j++) {
            xv[j] = *(const float4*)(x + i0 + j * 4);
            pv[j] = *(const float4*)(pe + i0 + j * 4);
        }
        #pragma unroll
        for (int h8 = 0; h8 < 2; h8++) {
            us8 o;
            #pragma unroll
            for (int j = 0; j < 2; j++) {
                float4 a = xv[h8 * 2 + j], p = pv[h8 * 2 + j];
                o[j * 4 + 0] = f2bf(a.x + p.x);
                o[j * 4 + 1] = f2bf(a.y + p.y);
                o[j * 4 + 2] = f2bf(a.z + p.z);
                o[j * 4 + 3] = f2bf(a.w + p.w);
            }
            *(us8*)(Abf + i0 + h8 * 8) = o;
        }
    } else {                                // wqkv^T: 8 x 48 tiles (64c x 128r)
        const int b2 = bid - 768;
        tr_direct8(wqkv, Wqkvt, C_DIM, N3C, (b2 / 48) * 128, (b2 % 48) * 64, tid);
    }
}

// ---------------------------------------------------------------------------
// qkv_fused: blocks [0,1152) = qkv GEMM (128x64 tiles); [1152,2688) = mv
// transpose; [2688,5760) = mk cast; [5760,5888) = wout^T. Prep branches are
// memory-only and overlap the GEMM's MFMA work on shared CUs.
// ---------------------------------------------------------------------------
__global__ __launch_bounds__(256) void qkv_fused(
    const u16* __restrict__ Abf, const u16* __restrict__ Wt,
    const float* __restrict__ bias,
    u16* __restrict__ Qw, u16* __restrict__ Kw, u16* __restrict__ Vwt,
    const float* __restrict__ mk, u16* __restrict__ mk_bf,
    const float* __restrict__ mv, u16* __restrict__ mv_t,
    const float* __restrict__ wout, u16* __restrict__ Woutt,
    const unsigned char* __restrict__ terminal, const int* __restrict__ mem_len)
{
    __shared__ u16 smem[128 * 64 + 64 * 64];   // As | Bs ; Cs aliases (128*72)
    const int bid = blockIdx.x;
    const int tid = threadIdx.x;

    if (bid >= 1152) {
        if (bid < 2688) {                   // mv transpose (skip t0 >= Lc)
            const int b5 = bid - 1152;
            const int bh = b5 & 127, tg = b5 >> 7;
            const int t0 = tg * 128;
            const int b = bh >> 4;
            const int L = terminal[b] ? 0 : mem_len[b];
            const int Lc = ((L + 63) >> 6) << 6;
            if (t0 >= Lc) return;
            const int cc4 = (tid & 15) * 4;
            const int tq = t0 + (tid >> 4) * 8;
            float4 Lv[8];
            #pragma unroll
            for (int k = 0; k < 8; k++)
                Lv[k] = *(const float4*)(mv + ((size_t)(tq + k) * 128 + bh) * 64 + cc4);
            #pragma unroll
            for (int j = 0; j < 4; j++) {
                us8 o;
                #pragma unroll
                for (int k = 0; k < 8; k++)
                    o[k] = f2bf(((const float*)&Lv[k])[j]);
                *(us8*)(mv_t + ((size_t)bh * 64 + cc4 + j) * M_DIM + tq) = o;
            }
        } else if (bid < 5760) {            // mk cast per (b, 4 t-rows) (skip)
            const int b6 = bid - 2688;
            const int b = b6 & 7, t0 = (b6 >> 3) * 4;
            const int L = terminal[b] ? 0 : mem_len[b];
            const int Lc = ((L + 63) >> 6) << 6;
            if (t0 >= Lc) return;
            const int r = t0 + (tid >> 6);
            const size_t rb = (size_t)r * 8192 + (size_t)b * 1024;
            const int cw = (tid & 63) * 4;
            float4 v[4];
            #pragma unroll
            for (int j = 0; j < 4; j++)
                v[j] = *(const float4*)(mk + rb + cw + j * 256);
            #pragma unroll
            for (int j = 0; j < 4; j++) {
                us4 o;
                o[0] = f2bf(v[j].x); o[1] = f2bf(v[j].y);
                o[2] = f2bf(v[j].z); o[3] = f2bf(v[j].w);
                *(us4*)(mk_bf + rb + cw + j * 256) = o;
            }
        } else {                            // wout^T: 8 x 16 tiles
            const int b7 = bid - 5760;
            tr_direct8(wout, Woutt, C_DIM, C_DIM, (b7 / 16) * 128, (b7 % 16) * 64, tid);
        }
        return;
    }

    // ---------------- qkv GEMM branch (bid < 1152) ----------------
    u16* As = smem;
    u16* Bs = smem + 128 * 64;
    u16* Cs = smem;

    const int lane = tid & 63, w = tid >> 6;
    const int lr = lane & 15, quad = lane >> 4;
    const int wm = w >> 1, wn = w & 1;
    const int row0 = (bid / 48) * 128, col0 = (bid % 48) * 64;

    f4v acc[4][2];
    #pragma unroll
    for (int i = 0; i < 4; i++)
        #pragma unroll
        for (int j = 0; j < 2; j++)
            acc[i][j] = (f4v){0.f, 0.f, 0.f, 0.f};

    for (int k0 = 0; k0 < C_DIM; k0 += 64) {
        __syncthreads();
        #pragma unroll
        for (int j = 0; j < 4; j++) {
            int idx = j * 256 + tid;
            int r = idx >> 3, c = (idx & 7) ^ (r & 7);
            gload16(&Abf[(size_t)(row0 + r) * C_DIM + k0 + c * 8], &As[idx * 8]);
        }
        #pragma unroll
        for (int j = 0; j < 2; j++) {
            int idx = j * 256 + tid;
            int r = idx >> 3, c = (idx & 7) ^ (r & 7);
            gload16(&Wt[(size_t)(col0 + r) * C_DIM + k0 + c * 8], &Bs[idx * 8]);
        }
        __syncthreads();
        #pragma unroll
        for (int kh = 0; kh < 2; kh++) {
            bf8v a[4], b[2];
            #pragma unroll
            for (int mi = 0; mi < 4; mi++) {
                int row = wm * 64 + mi * 16 + lr;
                int p = (kh * 4 + quad) ^ (lr & 7);
                a[mi] = *(const bf8v*)&As[row * 64 + p * 8];
            }
            #pragma unroll
            for (int nj = 0; nj < 2; nj++) {
                int row = wn * 32 + nj * 16 + lr;
                int p = (kh * 4 + quad) ^ (lr & 7);
                b[nj] = *(const bf8v*)&Bs[row * 64 + p * 8];
            }
            #pragma unroll
            for (int mi = 0; mi < 4; mi++)
                #pragma unroll
                for (int nj = 0; nj < 2; nj++)
                    acc[mi][nj] = __builtin_amdgcn_mfma_f32_16x16x32_bf16(a[mi], b[nj], acc[mi][nj], 0, 0, 0);
        }
    }

    const int which = col0 >> 10;
    const int h = (col0 >> 6) & 15;
    const float qs = (which == 0) ? QSCALE : 1.0f;

    __syncthreads();   // MFMA reads of As/Bs complete before Cs overwrite
    #pragma unroll
    for (int nj = 0; nj < 2; nj++) {
        int col = col0 + wn * 32 + nj * 16 + lr;
        float bv = bias[col];
        #pragma unroll
        for (int mi = 0; mi < 4; mi++)
            #pragma unroll
            for (int reg = 0; reg < 4; reg++)
                Cs[(wm * 64 + mi * 16 + quad * 4 + reg) * 72 + wn * 32 + nj * 16 + lr] =
                    f2bf((acc[mi][nj][reg] + bv) * qs);
    }
    __syncthreads();

    if (which != 2) {
        u16* dstbuf = (which == 0) ? Qw : Kw;
        int r = tid >> 1, half = tid & 1;
        int rg = row0 + r, s = rg >> 3, bb = rg & 7;
        u16* drow = dstbuf + ((size_t)(bb * 16 + h) * S_DIM + s) * 64 + half * 32;
        #pragma unroll
        for (int i = 0; i < 4; i++)
            *(us8*)(drow + i * 8) = *(const us8*)&Cs[r * 72 + half * 32 + i * 8];
    } else {
        int cc = tid & 63, w4 = tid >> 6;
        int s0 = row0 >> 3;
        #pragma unroll
        for (int pb = 0; pb < 2; pb++) {
            int bb = w4 * 2 + pb;
            us8 v0, v1;
            #pragma unroll
            for (int sl = 0; sl < 8; sl++) {
                v0[sl] = Cs[(sl * 8 + bb) * 72 + cc];
                v1[sl] = Cs[((sl + 8) * 8 + bb) * 72 + cc];
            }
            u16* dr = Vwt + ((size_t)(bb * 16 + h) * 64 + cc) * S_DIM + s0;
            *(us8*)dr = v0;
            *(us8*)(dr + 8) = v1;
        }
    }
}

// ---------------------------------------------------------------------------
// attn_split — proven best (R5-V2, 47.0us): 256 thr, 16KB single-buffer,
// __syncthreads loop, defer-max, cvt_pk pack, 32-bit strides, setprio.
// R3/R4/R6/R7 structural variants all null/regressed; V0 ablation shows the
// staging+sync floor runs at ~2.5TB/s — the memory-system rate for this
// traffic. Do not touch without new counter evidence.
// ---------------------------------------------------------------------------
__global__ __launch_bounds__(256) void attn_split(
    const u16* __restrict__ Qw, const u16* __restrict__ Kw,
    const u16* __restrict__ mk_bf, const u16* __restrict__ Vwt,
    const u16* __restrict__ mv_t, const unsigned char* __restrict__ terminal,
    const int* __restrict__ mem_len, u16* __restrict__ Op, float* __restrict__ ml)
{
    __shared__ u16 Ks[64 * 64];   // [t][cc], chunk-swizzled
    __shared__ u16 Vs[64 * 64];   // [cc][t], chunk-swizzled

    const int tid = threadIdx.x;
    const int lane = tid & 63, w = tid >> 6;
    const int lr = lane & 15, quad = lane >> 4, q8 = quad * 8;
    const int bid = blockIdx.x;
    const int j = bid % MAXS;
    const int g = bid / MAXS;                       // bhsc
    const int b = g & 7, h = (g >> 3) & 15, sc = g >> 7;
    const int bh = b * 16 + h, sq0 = sc * 64;
    const int L = terminal[b] ? 0 : mem_len[b];
    const int memChunks = (L + 63) >> 6;
    const int total = memChunks + sc + 1;
    const int lo = j * CHUNK;
    const int hi = (lo + CHUNK < total) ? lo + CHUNK : total;
    if (lo >= total) return;                        // inactive slot

    const int qrow = sq0 + w * 16 + lr;

    // Q as B-fragment (pre-scaled by QSCALE in qkv epilogue)
    const u16* qbase = Qw + ((size_t)bh * S_DIM + sq0 + w * 16 + lr) * 64;
    bf8v qf0 = *(const bf8v*)&qbase[q8];
    bf8v qf1 = *(const bf8v*)&qbase[32 + q8];

    f4v O[4];
    #pragma unroll
    for (int nj = 0; nj < 4; nj++) O[nj] = (f4v){0.f, 0.f, 0.f, 0.f};
    float m_i = -1e30f, l_i = 0.0f;

    const f4v zero = (f4v){0.f, 0.f, 0.f, 0.f};

    for (int ch = lo; ch < hi; ch++) {
        const bool isMem = (ch < memChunks);
        const int tloc = isMem ? ch * 64 : (ch - memChunks) * 64;
        const u16* kb; unsigned kstr;
        if (isMem) { kb = mk_bf + ((size_t)tloc * 128 + bh) * 64; kstr = 128u * 64u; }
        else       { kb = Kw + ((size_t)bh * S_DIM + tloc) * 64; kstr = 64u; }
        const u16* vb; unsigned vstr;
        if (isMem) { vb = mv_t + (size_t)bh * 64 * M_DIM + tloc; vstr = M_DIM; }
        else       { vb = Vwt + (size_t)bh * 64 * S_DIM + tloc; vstr = S_DIM; }

        __syncthreads();   // previous chunk's consumers done
        #pragma unroll
        for (int jj = 0; jj < 2; jj++) {           // Ks: 64 rows x 8 chunks
            int idx = jj * 256 + tid;
            unsigned r = idx >> 3, c = (idx & 7) ^ (r & 7);
            gload16(kb + r * kstr + c * 8u, &Ks[idx * 8]);
        }
        #pragma unroll
        for (int jj = 0; jj < 2; jj++) {           // Vs: 64 cc-rows x 8 chunks
            int idx = jj * 256 + tid;
            unsigned cc = idx >> 3, c = (idx & 7) ^ (cc & 7);
            gload16(vb + cc * vstr + c * 8u, &Vs[idx * 8]);
        }
        __syncthreads();

        // S^T tiles: sv[tt] covers t = tloc + tt*16 + quad*4 + reg, q = lane&15
        f4v sv[4];
        __builtin_amdgcn_s_setprio(1);
        #pragma unroll
        for (int tt = 0; tt < 4; tt++) {
            int row = tt * 16 + lr;
            int p0 = quad ^ (lr & 7), p1 = (4 + quad) ^ (lr & 7);
            bf8v k0 = *(const bf8v*)&Ks[row * 64 + p0 * 8];
            bf8v k1 = *(const bf8v*)&Ks[row * 64 + p1 * 8];
            sv[tt] = __builtin_amdgcn_mfma_f32_16x16x32_bf16(k0, qf0, zero, 0, 0, 0);
            sv[tt] = __builtin_amdgcn_mfma_f32_16x16x32_bf16(k1, qf1, sv[tt], 0, 0, 0);
        }
        __builtin_amdgcn_s_setprio(0);

        // Mask — wave-uniform skip (only boundary/diagonal chunks pay)
        if (isMem) {
            if (tloc + 64 > L) {
                #pragma unroll
                for (int tt = 0; tt < 4; tt++)
                    #pragma unroll
                    for (int reg = 0; reg < 4; reg++) {
                        int t = tloc + tt * 16 + quad * 4 + reg;
                        if (t >= L) sv[tt][reg] = -1e30f;
                    }
            }
        } else {
            if (tloc + 63 > sq0 + w * 16) {
                #pragma unroll
                for (int tt = 0; tt < 4; tt++)
                    #pragma unroll
                    for (int reg = 0; reg < 4; reg++) {
                        int t = tloc + tt * 16 + quad * 4 + reg;
                        if (t > qrow) sv[tt][reg] = -1e30f;
                    }
            }
        }

        // Online softmax, exp2 domain; reduce across lanes q,q+16,q+32,q+48
        float rowmax = fmaxf(fmaxf(sv[0][0], sv[0][1]), fmaxf(sv[0][2], sv[0][3]));
        #pragma unroll
        for (int tt = 1; tt < 4; tt++)
            rowmax = fmaxf(rowmax, fmaxf(fmaxf(sv[tt][0], sv[tt][1]),
                                         fmaxf(sv[tt][2], sv[tt][3])));
        rowmax = fmaxf(rowmax, __shfl_xor(rowmax, 16));
        rowmax = fmaxf(rowmax, __shfl_xor(rowmax, 32));

        // T13 defer-max: skip rescale when max grew by <= 8 (P bounded 2^8)
        const bool defer = __all(rowmax - m_i <= 8.0f);
        const float mnew = defer ? m_i : fmaxf(m_i, rowmax);

        float p[16];
        float s0 = 0.f, s1 = 0.f, s2 = 0.f, s3 = 0.f;
        #pragma unroll
        for (int tt = 0; tt < 4; tt++) {
            p[tt * 4 + 0] = EX2(sv[tt][0] - mnew);
            p[tt * 4 + 1] = EX2(sv[tt][1] - mnew);
            p[tt * 4 + 2] = EX2(sv[tt][2] - mnew);
            p[tt * 4 + 3] = EX2(sv[tt][3] - mnew);
            s0 += p[tt * 4 + 0]; s1 += p[tt * 4 + 1];
            s2 += p[tt * 4 + 2]; s3 += p[tt * 4 + 3];
        }
        float sum = (s0 + s1) + (s2 + s3);
        sum += __shfl_xor(sum, 16);
        sum += __shfl_xor(sum, 32);

        bf4v pf[4];
        #pragma unroll
        for (int tt = 0; tt < 4; tt++) {
            union { bf4v v; unsigned u[2]; } pu;
            pu.u[0] = cvtpk_bf16(p[tt * 4 + 0], p[tt * 4 + 1]);
            pu.u[1] = cvtpk_bf16(p[tt * 4 + 2], p[tt * 4 + 3]);
            pf[tt] = pu.v;
        }

        if (defer) {
            l_i += sum;                        // alpha == 1, O untouched
        } else {
            float alpha = EX2(m_i - mnew);
            m_i = mnew;
            l_i = l_i * alpha + sum;
            float alphaR[4];
            #pragma unroll
            for (int reg = 0; reg < 4; reg++)
                alphaR[reg] = __shfl(alpha, quad * 4 + reg);
            #pragma unroll
            for (int nj = 0; nj < 4; nj++)
                #pragma unroll
                for (int reg = 0; reg < 4; reg++)
                    O[nj][reg] *= alphaR[reg];
        }

        // PV: A = P (regs), B = V from Vs[cc][t] (de-swizzled bf4v reads)
        __builtin_amdgcn_s_setprio(1);
        #pragma unroll
        for (int tt = 0; tt < 4; tt++) {
            #pragma unroll
            for (int nj = 0; nj < 4; nj++) {
                int cc = nj * 16 + lr;
                int c = (tt * 2 + (quad >> 1)) ^ (lr & 7);
                bf4v vf = *(const bf4v*)&Vs[cc * 64 + c * 8 + (quad & 1) * 4];
                O[nj] = mfma16x16x16bf16(pf[tt], vf, O[nj]);
            }
        }
        __builtin_amdgcn_s_setprio(0);
    }

    // Write partials (unnormalized O, m, l) — slot (g, j)
    const size_t pbase = (size_t)(g * MAXS + j) * 64;
    if (quad == 0) {
        int row = w * 16 + lr;
        float2 mlv = {m_i, l_i};
        *(float2*)&ml[(pbase + row) * 2] = mlv;
    }
    #pragma unroll
    for (int reg = 0; reg < 4; reg++) {
        int row = w * 16 + quad * 4 + reg;
        #pragma unroll
        for (int nj = 0; nj < 4; nj++)
            Op[(pbase + row) * 64 + nj * 16 + lr] = f2bf(O[nj][reg]);
    }
}

// ---------------------------------------------------------------------------
// attn_combine: merge the valid slots (j*CHUNK < total_g) -> Obf bf16
// ---------------------------------------------------------------------------
__global__ __launch_bounds__(256) void attn_combine(
    const unsigned char* __restrict__ terminal, const int* __restrict__ mem_len,
    const u16* __restrict__ Op, const float* __restrict__ ml, u16* __restrict__ Obf)
{
    const int g = blockIdx.x;                       // bhsc
    const int b = g & 7, h = (g >> 3) & 15, sc = g >> 7;
    const int tid = threadIdx.x;
    const int row = tid >> 2, c0 = (tid & 3) * 16;

    const int L = terminal[b] ? 0 : mem_len[b];
    const int total = ((L + 63) >> 6) + sc + 1;
    const int nsp = (total + CHUNK - 1) / CHUNK;    // valid slots

    float m[MAXS], lv[MAXS];
    #pragma unroll
    for (int j = 0; j < MAXS; j++) {
        if (j < nsp) {
            size_t base = (size_t)(g * MAXS + j) * 64 + row;
            m[j]  = ml[base * 2];
            lv[j] = ml[base * 2 + 1];
        } else { m[j] = -1e30f; lv[j] = 0.0f; }
    }
    float mstar = m[0];
    #pragma unroll
    for (int j = 1; j < MAXS; j++) mstar = fmaxf(mstar, m[j]);
    float sc_j[MAXS], l = 0.0f;
    #pragma unroll
    for (int j = 0; j < MAXS; j++) {
        sc_j[j] = (j < nsp) ? EX2(m[j] - mstar) : 0.0f;   // exp2 domain
        l += sc_j[j] * lv[j];
    }
    float inv = 1.0f / l;

    float o[16];
    #pragma unroll
    for (int c = 0; c < 16; c++) o[c] = 0.0f;
    for (int j = 0; j < nsp; j++) {
        const u16* src = &Op[((size_t)(g * MAXS + j) * 64 + row) * 64 + c0];
        us8 v0 = *(const us8*)src;
        us8 v1 = *(const us8*)(src + 8);
        #pragma unroll
        for (int c = 0; c < 8; c++) {
            o[c]     += sc_j[j] * bf2f(v0[c]);
            o[c + 8] += sc_j[j] * bf2f(v1[c]);
        }
    }
    int s = sc * 64 + row;
    size_t dst = ((size_t)s * 8 + b) * C_DIM + h * 64 + c0;
    us8 w0, w1;
    #pragma unroll
    for (int c = 0; c < 8; c++) {
        w0[c] = f2bf(o[c] * inv);
        w1[c] = f2bf(o[c + 8] * inv);
    }
    *(us8*)&Obf[dst] = w0;
    *(us8*)&Obf[dst + 8] = w1;
}

// ---------------------------------------------------------------------------
// proj GEMM: 64x64 tiles, BK=64, swizzled DMA staging.
// ---------------------------------------------------------------------------
__global__ __launch_bounds__(256) void proj_gemm(
    const u16* __restrict__ Abf, const u16* __restrict__ Wt,
    const float* __restrict__ bias, float* __restrict__ out)
{
    __shared__ u16 As[64 * 64];
    __shared__ u16 Bs[64 * 64];
    const int tid = threadIdx.x;
    const int lane = tid & 63, w = tid >> 6;
    const int lr = lane & 15, quad = lane >> 4;
    const int row0 = blockIdx.y * 64, col0 = blockIdx.x * 64;

    f4v acc[4];
    #pragma unroll
    for (int i = 0; i < 4; i++) acc[i] = (f4v){0.f, 0.f, 0.f, 0.f};

    for (int k0 = 0; k0 < C_DIM; k0 += 64) {
        __syncthreads();
        #pragma unroll
        for (int j = 0; j < 2; j++) {
            int idx = j * 256 + tid;
            int r = idx >> 3, c = (idx & 7) ^ (r & 7);
            gload16(&Abf[(size_t)(row0 + r) * C_DIM + k0 + c * 8], &As[idx * 8]);
            gload16(&Wt[(size_t)(col0 + r) * C_DIM + k0 + c * 8], &Bs[idx * 8]);
        }
        __syncthreads();
        #pragma unroll
        for (int kh = 0; kh < 2; kh++) {
            int p = (kh * 4 + quad) ^ (lr & 7);
            bf8v a = *(const bf8v*)&As[(w * 16 + lr) * 64 + p * 8];
            #pragma unroll
            for (int nj = 0; nj < 4; nj++) {
                bf8v bfr = *(const bf8v*)&Bs[(nj * 16 + lr) * 64 + p * 8];
                acc[nj] = __builtin_amdgcn_mfma_f32_16x16x32_bf16(a, bfr, acc[nj], 0, 0, 0);
            }
        }
    }

    #pragma unroll
    for (int nj = 0; nj < 4; nj++) {
        int col = col0 + nj * 16 + lr;
        float bv = bias[col];
        #pragma unroll
        for (int reg = 0; reg < 4; reg++) {
            int rg = row0 + w * 16 + quad * 4 + reg;
            out[(size_t)rg * C_DIM + col] = acc[nj][reg] + bv;
        }
    }
}

// ---------------------------------------------------------------------------
extern "C" void kernel_launch(void* const* d_in, const int* in_sizes, int n_in,
                              void* d_out, int out_size, void* d_ws, size_t ws_size,
                              hipStream_t stream) {
    const float* x    = (const float*)d_in[0];
    const float* pe   = (const float*)d_in[1];
    const float* mk   = (const float*)d_in[2];
    const float* mv   = (const float*)d_in[3];
    const float* wqkv = (const float*)d_in[4];
    const float* bqkv = (const float*)d_in[5];
    const float* wout = (const float*)d_in[6];
    const float* bout = (const float*)d_in[7];
    const unsigned char* term = (const unsigned char*)d_in[8];
    // d_in[9] content_mask (causal, analytic), d_in[10] padding_mask (all False)
    const int* mem_len = (const int*)d_in[11];

    char* ws = (char*)d_ws;
    u16* Abf   = (u16*)(ws + 0);          // 6291456 B  (Obf aliases after qkv)
    u16* Obf   = (u16*)(ws + 0);
    u16* Wqkvt = (u16*)(ws + 6291456);    // 6291456 B  (ml aliases after qkv)
    float* ml  = (float*)(ws + 6291456);  // 1966080 B  (768*5*64*2 f32)
    u16* Woutt = (u16*)(ws + 12582912);   // 2097152 B
    u16* mk_bf = (u16*)(ws + 14680064);   // 25165824 B  [t][bh][cc] bf16 (cast only)
    u16* mv_t  = (u16*)(ws + 39845888);   // 25165824 B  [bh][cc][t]
    u16* Qw    = (u16*)(ws + 65011712);   // 6291456 B
    u16* Kw    = (u16*)(ws + 71303168);   // 6291456 B
    u16* Vwt   = (u16*)(ws + 77594624);   // 6291456 B  [bh][cc][s] (written by qkv)
    u16* Op    = (u16*)(ws + 83886080);   // 31457280 B (768*5*64*64 bf16) end 115343360

    float* out = (float*)d_out;

    prep_early<<<1152, 256, 0, stream>>>(x, pe, Abf, wqkv, Wqkvt);

    qkv_fused<<<5888, 256, 0, stream>>>(
        Abf, Wqkvt, bqkv, Qw, Kw, Vwt,
        mk, mk_bf, mv, mv_t, wout, Woutt, term, mem_len);

    attn_split<<<B_DIM * H_DIM * (S_DIM / 64) * MAXS, 256, 0, stream>>>(
        Qw, Kw, mk_bf, Vwt, mv_t, term, mem_len, Op, ml);

    attn_combine<<<B_DIM * H_DIM * (S_DIM / 64), 256, 0, stream>>>(
        term, mem_len, Op, ml, Obf);

    proj_gemm<<<dim3(C_DIM / 64, ROWS / 64), 256, 0, stream>>>(
        Obf, Woutt, bout, out);
}